// Round 2
// baseline (332.729 us; speedup 1.0000x reference)
//
#include <hip/hip_runtime.h>
#include <hip/hip_bf16.h>

// SEAL GCN: 3x GraphConv(norm=both) -> SumPool(graph_id sorted) -> MLP(128->128 relu ->200)
// N=50000, E=800000, feat=128, 512 graphs.
// R12: gather ILP 8->16 deep (latency-bound: VALUBusy 18%), gather_pool LDS-atomic-free
//      segmented reduction (per-node LDS rows + sorted-gid run flush), CH 128->64
//      (k_merge serial chunk loop halved; partials traffic halved).

#define FEAT 128
#define NG 512
#define CH 64        // edge chunks for hist/fill
#define NPMAX 12544  // max node-quads (N<=50176); 50KB static LDS
#define LDW 136      // LDS row stride in ushorts (bf16): 2-way-free banks for b128

typedef __attribute__((ext_vector_type(8))) short bf16x8;
typedef __attribute__((ext_vector_type(4))) float f32x4;

__device__ __forceinline__ float bf2f(unsigned short u) {
    union { unsigned int i; float f; } v; v.i = ((unsigned int)u) << 16; return v.f;
}
__device__ __forceinline__ unsigned short f2bf(float f) {
    unsigned int u = __float_as_uint(f);
    return (unsigned short)((u + 0x7FFFu + ((u >> 16) & 1u)) >> 16);  // RNE
}
__device__ __forceinline__ float lo16(unsigned u) { return __uint_as_float(u << 16); }
__device__ __forceinline__ float hi16(unsigned u) { return __uint_as_float(u & 0xFFFF0000u); }

// ---------------- chunked full-range histogram, packed u8, zero global atomics ----------------
__global__ __launch_bounds__(256) void k_hist(
        const int* __restrict__ src, const int* __restrict__ dst,
        unsigned* __restrict__ partial_out, unsigned* __restrict__ partial_in,
        int E, int NP, int Ec) {
    __shared__ unsigned h[NPMAX];
    int tid = threadIdx.x;
    int b = blockIdx.x;
    int c = b & (CH - 1);
    const int* __restrict__ arr = (b < CH) ? src : dst;
    unsigned* __restrict__ outp = ((b < CH) ? partial_out : partial_in) + (size_t)c * NP;
    for (int i = tid; i < NP; i += 256) h[i] = 0;
    __syncthreads();
    int e0 = c * Ec, e1 = min(E, e0 + Ec);
    for (int e = e0 + tid; e < e1; e += 256) {
        int v = arr[e];
        atomicAdd(&h[v >> 2], 1u << ((v & 3) * 8));
    }
    __syncthreads();
    for (int i = tid; i < NP; i += 256) outp[i] = h[i];
}

// ---------------- merge partials: totals + in-place exclusive chunk-prefix ----------------
__global__ void k_merge(unsigned* __restrict__ partial_out, unsigned* __restrict__ partial_in,
                        int* __restrict__ cnt_in, float* __restrict__ norm_out,
                        float* __restrict__ norm_in, int N, int NP) {
    int w = blockIdx.x * blockDim.x + threadIdx.x;
    if (w >= NP) return;
    unsigned run_in = 0, run_out = 0;
    for (int c = 0; c < CH; c++) {
        size_t idx = (size_t)c * NP + w;
        unsigned v = partial_in[idx];
        partial_in[idx] = run_in;
        run_in += v;
        run_out += partial_out[idx];
    }
    #pragma unroll
    for (int j = 0; j < 4; j++) {
        int node = w * 4 + j;
        if (node < N) {
            unsigned di = (run_in  >> (j * 8)) & 255u;
            unsigned dd = (run_out >> (j * 8)) & 255u;
            cnt_in[node]   = (int)di;
            norm_in[node]  = rsqrtf(fmaxf((float)di, 1.0f));
            norm_out[node] = rsqrtf(fmaxf((float)dd, 1.0f));
        }
    }
}

// ---------------- 2-level exclusive scan of cnt_in -> row_start ----------------
__global__ void k_scan_local(const int* __restrict__ cnt, int* __restrict__ excl,
                             int* __restrict__ bsum, int N) {
    __shared__ int s[256];
    int x = threadIdx.x;
    int i = blockIdx.x * 256 + x;
    int v = (i < N) ? cnt[i] : 0;
    s[x] = v;
    __syncthreads();
    for (int off = 1; off < 256; off <<= 1) {
        int t = (x >= off) ? s[x - off] : 0;
        __syncthreads();
        s[x] += t;
        __syncthreads();
    }
    if (i < N) excl[i] = s[x] - v;
    if (x == 255) bsum[blockIdx.x] = s[255];
}

// block 0: scan of block sums; blocks 1..128: pack W0,W1 -> bf16 MFMA B-fragment order
// WF[f][lane][e] with f=nt*4+fi, lane=q*16+c: value = W[k*128+n], n=nt*16+c, k=fi*32+q*8+e
__global__ void k_scan_bsum_prep(int* __restrict__ bsum, int* __restrict__ boff, int nb,
                                 const float* __restrict__ W0, const float* __restrict__ W1,
                                 unsigned short* __restrict__ WF0, unsigned short* __restrict__ WF1) {
    if (blockIdx.x == 0) {
        __shared__ int s[256];
        int x = threadIdx.x;
        int v = (x < nb) ? bsum[x] : 0;
        s[x] = v;
        __syncthreads();
        for (int off = 1; off < 256; off <<= 1) {
            int t = (x >= off) ? s[x - off] : 0;
            __syncthreads();
            s[x] += t;
            __syncthreads();
        }
        if (x < nb) boff[x] = s[x] - v;
    } else {
        int t = ((int)blockIdx.x - 1) * 256 + threadIdx.x;  // 0..32767
        const float* __restrict__ W = (t < 16384) ? W0 : W1;
        unsigned short* __restrict__ WF = (t < 16384) ? WF0 : WF1;
        int tt = t & 16383;
        int f = tt >> 9, l = (tt >> 3) & 63, e = tt & 7;
        int n = (f >> 2) * 16 + (l & 15);
        int k = (f & 3) * 32 + (l >> 4) * 8 + e;
        WF[tt] = f2bf(W[k * 128 + n]);
    }
}

__global__ void k_add_off(int* __restrict__ row_start, const int* __restrict__ boff,
                          float* __restrict__ g, int N) {
    int i = blockIdx.x * blockDim.x + threadIdx.x;
    int stride = gridDim.x * blockDim.x;
    if (i < N) row_start[i] += boff[i >> 8];
    for (int j = i; j < NG * FEAT; j += stride) g[j] = 0.f;  // zero pooled accum
}

// ---------------- chunked CSR fill (LDS cursors, packed u8, u16 csr) + build x0 ----------------
__global__ __launch_bounds__(256) void k_fill_bx(
        const int* __restrict__ src, const int* __restrict__ dst,
        const int* __restrict__ row_start, const unsigned* __restrict__ partial_in,
        unsigned short* __restrict__ csr,
        const int* __restrict__ nid, const int* __restrict__ z,
        const float* __restrict__ emb, const float* __restrict__ zt,
        const float* __restrict__ nout, unsigned short* __restrict__ x,
        int N, int E, int NP, int Ec) {
    if ((int)blockIdx.x < CH) {
        __shared__ unsigned cur[NPMAX];
        int tid = threadIdx.x;
        int c = blockIdx.x;
        const unsigned* __restrict__ pre = partial_in + (size_t)c * NP;
        for (int i = tid; i < NP; i += 256) cur[i] = pre[i];
        __syncthreads();
        int e0 = c * Ec, e1 = min(E, e0 + Ec);
        for (int e = e0 + tid; e < e1; e += 256) {
            int d = dst[e], s = src[e];
            int sh = (d & 3) * 8;
            unsigned t = atomicAdd(&cur[d >> 2], 1u << sh);
            int off = (int)((t >> sh) & 255u);
            csr[row_start[d] + off] = (unsigned short)s;
        }
    } else {
        int tid = ((int)blockIdx.x - CH) * 256 + threadIdx.x;
        int i = tid >> 5, q = tid & 31;
        if (i < N) {
            float4 v;
            if (q < 16) v = ((const float4*)emb)[(size_t)nid[i] * 16 + q];
            else        v = ((const float4*)zt)[(size_t)z[i] * 16 + (q - 16)];
            float w = nout[i];
            ushort4 u;
            u.x = f2bf(v.x * w); u.y = f2bf(v.y * w);
            u.z = f2bf(v.z * w); u.w = f2bf(v.w * w);
            ((ushort4*)x)[(size_t)i * 32 + q] = u;
        }
    }
}

// ---------------- gather core: b128 loads, 16 lanes/node, 16-deep ILP ----------------
#define ACC8(u)                                                                  \
    a0 += lo16(u.x); a1 += hi16(u.x); a2 += lo16(u.y); a3 += hi16(u.y);          \
    a4 += lo16(u.z); a5 += hi16(u.z); a6 += lo16(u.w); a7 += hi16(u.w);

#define GATHER_LOOP                                                              \
    {                                                                            \
        int base = row_start[node];                                              \
        int n = cnt_in[node];                                                    \
        const uint4* xp = (const uint4*)x;  /* row = 16 uint4 */                 \
        int j0 = 0;                                                              \
        for (; j0 + 16 <= n; j0 += 16) {                                         \
            int e = (int)csr[base + j0 + ql];                                    \
            int s0 = __shfl(e, 0, 16),   s1 = __shfl(e, 1, 16);                  \
            int s2 = __shfl(e, 2, 16),   s3 = __shfl(e, 3, 16);                  \
            int s4 = __shfl(e, 4, 16),   s5 = __shfl(e, 5, 16);                  \
            int s6 = __shfl(e, 6, 16),   s7 = __shfl(e, 7, 16);                  \
            int s8 = __shfl(e, 8, 16),   s9 = __shfl(e, 9, 16);                  \
            int s10 = __shfl(e, 10, 16), s11 = __shfl(e, 11, 16);                \
            int s12 = __shfl(e, 12, 16), s13 = __shfl(e, 13, 16);                \
            int s14 = __shfl(e, 14, 16), s15 = __shfl(e, 15, 16);                \
            uint4 u0  = xp[(size_t)s0 * 16 + ql];                                \
            uint4 u1  = xp[(size_t)s1 * 16 + ql];                                \
            uint4 u2  = xp[(size_t)s2 * 16 + ql];                                \
            uint4 u3  = xp[(size_t)s3 * 16 + ql];                                \
            uint4 u4  = xp[(size_t)s4 * 16 + ql];                                \
            uint4 u5  = xp[(size_t)s5 * 16 + ql];                                \
            uint4 u6  = xp[(size_t)s6 * 16 + ql];                                \
            uint4 u7  = xp[(size_t)s7 * 16 + ql];                                \
            uint4 u8  = xp[(size_t)s8 * 16 + ql];                                \
            uint4 u9  = xp[(size_t)s9 * 16 + ql];                                \
            uint4 u10 = xp[(size_t)s10 * 16 + ql];                               \
            uint4 u11 = xp[(size_t)s11 * 16 + ql];                               \
            uint4 u12 = xp[(size_t)s12 * 16 + ql];                               \
            uint4 u13 = xp[(size_t)s13 * 16 + ql];                               \
            uint4 u14 = xp[(size_t)s14 * 16 + ql];                               \
            uint4 u15 = xp[(size_t)s15 * 16 + ql];                               \
            ACC8(u0)  ACC8(u1)  ACC8(u2)  ACC8(u3)                               \
            ACC8(u4)  ACC8(u5)  ACC8(u6)  ACC8(u7)                               \
            ACC8(u8)  ACC8(u9)  ACC8(u10) ACC8(u11)                              \
            ACC8(u12) ACC8(u13) ACC8(u14) ACC8(u15)                              \
        }                                                                        \
        int rem = n - j0;                                                        \
        if (rem > 0) {                                                           \
            int e = (int)csr[base + j0 + (ql < rem ? ql : 0)];                   \
            int j = 0;                                                           \
            for (; j + 8 <= rem; j += 8) {                                       \
                int s0 = __shfl(e, j + 0, 16), s1 = __shfl(e, j + 1, 16);        \
                int s2 = __shfl(e, j + 2, 16), s3 = __shfl(e, j + 3, 16);        \
                int s4 = __shfl(e, j + 4, 16), s5 = __shfl(e, j + 5, 16);        \
                int s6 = __shfl(e, j + 6, 16), s7 = __shfl(e, j + 7, 16);        \
                uint4 u0 = xp[(size_t)s0 * 16 + ql];                             \
                uint4 u1 = xp[(size_t)s1 * 16 + ql];                             \
                uint4 u2 = xp[(size_t)s2 * 16 + ql];                             \
                uint4 u3 = xp[(size_t)s3 * 16 + ql];                             \
                uint4 u4 = xp[(size_t)s4 * 16 + ql];                             \
                uint4 u5 = xp[(size_t)s5 * 16 + ql];                             \
                uint4 u6 = xp[(size_t)s6 * 16 + ql];                             \
                uint4 u7 = xp[(size_t)s7 * 16 + ql];                             \
                ACC8(u0) ACC8(u1) ACC8(u2) ACC8(u3)                              \
                ACC8(u4) ACC8(u5) ACC8(u6) ACC8(u7)                              \
            }                                                                    \
            for (; j + 4 <= rem; j += 4) {                                       \
                int s0 = __shfl(e, j + 0, 16), s1 = __shfl(e, j + 1, 16);        \
                int s2 = __shfl(e, j + 2, 16), s3 = __shfl(e, j + 3, 16);        \
                uint4 u0 = xp[(size_t)s0 * 16 + ql];                             \
                uint4 u1 = xp[(size_t)s1 * 16 + ql];                             \
                uint4 u2 = xp[(size_t)s2 * 16 + ql];                             \
                uint4 u3 = xp[(size_t)s3 * 16 + ql];                             \
                ACC8(u0) ACC8(u1) ACC8(u2) ACC8(u3)                              \
            }                                                                    \
            for (; j < rem; j++) {                                               \
                int s = __shfl(e, j, 16);                                        \
                uint4 u = xp[(size_t)s * 16 + ql];                               \
                ACC8(u)                                                          \
            }                                                                    \
        }                                                                        \
    }

// ---------------- fused gather + MFMA GEMM: y = relu((A_hat x) @ W + b) * nout ----------------
// 64 nodes/block; gather in 4 rounds of 16 nodes (16 lanes/node) straight into As LDS;
// W fragments read per-wave from L2-resident WF (coalesced 16B/lane, no LDS tile).
__global__ __launch_bounds__(256) void k_gather_gemm(
        const unsigned short* __restrict__ x, const float* __restrict__ nin,
        const unsigned short* __restrict__ csr, const int* __restrict__ row_start,
        const int* __restrict__ cnt_in, const unsigned short* __restrict__ WF,
        const float* __restrict__ bias, const float* __restrict__ nout,
        unsigned short* __restrict__ y, int N) {
    __shared__ unsigned short As[64 * LDW];  // 17.4KB
    int tid = threadIdx.x;
    int nb = blockIdx.x * 64;
    int ql = tid & 15;
    int nsub = tid >> 4;

    #pragma unroll 1
    for (int r = 0; r < 4; r++) {
        int node = nb + r * 16 + nsub;
        float a0 = 0.f, a1 = 0.f, a2 = 0.f, a3 = 0.f;
        float a4 = 0.f, a5 = 0.f, a6 = 0.f, a7 = 0.f;
        if (node < N) {
            GATHER_LOOP
            float ni = nin[node];
            a0 *= ni; a1 *= ni; a2 *= ni; a3 *= ni;
            a4 *= ni; a5 *= ni; a6 *= ni; a7 *= ni;
        }
        uint4 o;
        o.x = (unsigned)f2bf(a0) | ((unsigned)f2bf(a1) << 16);
        o.y = (unsigned)f2bf(a2) | ((unsigned)f2bf(a3) << 16);
        o.z = (unsigned)f2bf(a4) | ((unsigned)f2bf(a5) << 16);
        o.w = (unsigned)f2bf(a6) | ((unsigned)f2bf(a7) << 16);
        *(uint4*)(As + (r * 16 + nsub) * LDW + ql * 8) = o;
    }
    __syncthreads();

    int lane = tid & 63;
    int m0 = (tid >> 6) * 16;
    int c = lane & 15, q = lane >> 4;

    const unsigned short* ap = As + (m0 + c) * LDW + q * 8;
    bf16x8 fa0 = *(const bf16x8*)(ap);
    bf16x8 fa1 = *(const bf16x8*)(ap + 32);
    bf16x8 fa2 = *(const bf16x8*)(ap + 64);
    bf16x8 fa3 = *(const bf16x8*)(ap + 96);
    const bf16x8* __restrict__ wf = (const bf16x8*)WF;

    #pragma unroll
    for (int nt = 0; nt < 8; nt++) {
        bf16x8 fb0 = wf[(nt * 4 + 0) * 64 + lane];
        bf16x8 fb1 = wf[(nt * 4 + 1) * 64 + lane];
        bf16x8 fb2 = wf[(nt * 4 + 2) * 64 + lane];
        bf16x8 fb3 = wf[(nt * 4 + 3) * 64 + lane];
        float bb = bias[nt * 16 + c];
        f32x4 acc = {bb, bb, bb, bb};
        acc = __builtin_amdgcn_mfma_f32_16x16x32_bf16(fa0, fb0, acc, 0, 0, 0);
        acc = __builtin_amdgcn_mfma_f32_16x16x32_bf16(fa1, fb1, acc, 0, 0, 0);
        acc = __builtin_amdgcn_mfma_f32_16x16x32_bf16(fa2, fb2, acc, 0, 0, 0);
        acc = __builtin_amdgcn_mfma_f32_16x16x32_bf16(fa3, fb3, acc, 0, 0, 0);
        #pragma unroll
        for (int rr = 0; rr < 4; rr++) {
            int row = m0 + q * 4 + rr;
            float s = nout[min(nb + row, N - 1)];
            As[row * LDW + nt * 16 + c] = f2bf(fmaxf(acc[rr], 0.f) * s);
        }
    }
    __syncthreads();

    for (int i = tid; i < 64 * 16; i += 256) {
        int row = i >> 4, seg = i & 15;
        int node = nb + row;
        if (node < N) {
            const ushort4* p = (const ushort4*)(As + row * LDW + seg * 8);
            ushort4* d = (ushort4*)(y + (size_t)node * 128 + seg * 8);
            d[0] = p[0]; d[1] = p[1];
        }
    }
}

// ---------------- fused layer-2 gather + SumPool: g[gid] += (A_hat x)[node] ----------------
// graph_id sorted -> per-node LDS rows, then non-atomic segmented reduction over the
// sorted gid runs (<=16 per block); one coalesced global-atomic set per run-half.
__global__ __launch_bounds__(256) void k_gather_pool(
        const unsigned short* __restrict__ x, const float* __restrict__ nin,
        const unsigned short* __restrict__ csr, const int* __restrict__ row_start,
        const int* __restrict__ cnt_in, const int* __restrict__ gid,
        float* __restrict__ g, int N) {
    __shared__ __align__(16) float gl[16][132];  // per-node partials, +4 pad
    __shared__ int slots[16];
    int tid = threadIdx.x;
    int nb = blockIdx.x * 16;
    int ql = tid & 15;
    int nl = tid >> 4;
    int node = nb + nl;

    float a0 = 0.f, a1 = 0.f, a2 = 0.f, a3 = 0.f;
    float a4 = 0.f, a5 = 0.f, a6 = 0.f, a7 = 0.f;
    int slot = -1;
    if (node < N) {
        GATHER_LOOP
        float ni = nin[node];
        a0 *= ni; a1 *= ni; a2 *= ni; a3 *= ni;
        a4 *= ni; a5 *= ni; a6 *= ni; a7 *= ni;
        slot = gid[node];
    }
    float4* row = (float4*)&gl[nl][ql * 8];
    row[0] = make_float4(a0, a1, a2, a3);
    row[1] = make_float4(a4, a5, a6, a7);
    if (ql == 0) slots[nl] = slot;
    __syncthreads();

    int h = tid >> 7;       // 0/1: nodes 0-7 / 8-15
    int j = tid & 127;
    int prev = -1;
    float acc = 0.f;
    #pragma unroll
    for (int i = h * 8; i < h * 8 + 8; i++) {
        int s = slots[i];
        if (s != prev) {
            if (prev >= 0) atomicAdd(&g[(size_t)prev * FEAT + j], acc);
            acc = 0.f;
            prev = s;
        }
        acc += gl[i][j];
    }
    if (prev >= 0) atomicAdd(&g[(size_t)prev * FEAT + j], acc);
}

// ---------------- head: ys = g@W2 + cnt*b2 ; out = relu(ys@l1W+l1b)@l2W+l2b ----------------
__global__ __launch_bounds__(256) void k_head(
        const float* __restrict__ g, const int* __restrict__ gid,
        const float* __restrict__ W2, const float* __restrict__ b2,
        const float* __restrict__ l1W, const float* __restrict__ l1b,
        const float* __restrict__ l2W, const float* __restrict__ l2b,
        float* __restrict__ out, int N) {
    __shared__ float gs[128];
    __shared__ float ys[128];
    __shared__ float hs[128];
    int gi = blockIdx.x, tid = threadIdx.x;

    int lo = 0, hi = N;
    while (lo < hi) { int m = (lo + hi) >> 1; if (gid[m] < gi) lo = m + 1; else hi = m; }
    int s0 = lo;
    lo = 0; hi = N;
    while (lo < hi) { int m = (lo + hi) >> 1; if (gid[m] < gi + 1) lo = m + 1; else hi = m; }
    float cnt = (float)(lo - s0);

    if (tid < 128) gs[tid] = g[(size_t)gi * FEAT + tid];
    __syncthreads();
    if (tid < 128) {
        float a = cnt * b2[tid];
        for (int k = 0; k < 128; k++) a += gs[k] * W2[(size_t)k * 128 + tid];
        ys[tid] = a;
    }
    __syncthreads();
    if (tid < 128) {
        float a = l1b[tid];
        for (int k = 0; k < 128; k++) a += ys[k] * l1W[(size_t)k * 128 + tid];
        hs[tid] = fmaxf(a, 0.f);
    }
    __syncthreads();
    if (tid < 200) {
        float a = l2b[tid];
        for (int k = 0; k < 128; k++) a += hs[k] * l2W[(size_t)k * 200 + tid];
        out[(size_t)gi * 200 + tid] = a;
    }
}

extern "C" void kernel_launch(void* const* d_in, const int* in_sizes, int n_in,
                              void* d_out, int out_size, void* d_ws, size_t ws_size,
                              hipStream_t stream) {
    const int*   nid = (const int*)d_in[0];
    const int*   z   = (const int*)d_in[1];
    const int*   src = (const int*)d_in[2];
    const int*   dst = (const int*)d_in[3];
    const int*   gid = (const int*)d_in[4];
    const float* emb = (const float*)d_in[5];
    const float* zt  = (const float*)d_in[6];
    const float* W0  = (const float*)d_in[7];
    const float* b0  = (const float*)d_in[8];
    const float* W1  = (const float*)d_in[9];
    const float* b1  = (const float*)d_in[10];
    const float* W2  = (const float*)d_in[11];
    const float* b2  = (const float*)d_in[12];
    const float* l1W = (const float*)d_in[13];
    const float* l1b = (const float*)d_in[14];
    const float* l2W = (const float*)d_in[15];
    const float* l2b = (const float*)d_in[16];
    float* out = (float*)d_out;

    const int N = in_sizes[0];
    const int E = in_sizes[2];
    const int NB = (N + 255) / 256;     // scan blocks (<=256 required)
    const int NP = (N + 3) / 4;         // node-quads (<= NPMAX)
    const int Ec = (E + CH - 1) / CH;   // edges per chunk

    // ---- workspace ----
    size_t NA = (size_t)((N + 63) & ~63);
    float* norm_out = (float*)d_ws;                      // NA
    float* norm_in  = norm_out + NA;                     // NA
    float* g        = norm_in + NA;                      // NG*FEAT fp32 pooled accum
    unsigned short* xA  = (unsigned short*)(g + (size_t)NG * FEAT);  // N*128 bf16
    unsigned short* xB  = xA + (size_t)N * FEAT;         // N*128 bf16
    unsigned short* WF0 = xB + (size_t)N * FEAT;         // 128*128 bf16 (fragment order)
    unsigned short* WF1 = WF0 + 128 * 128;               // 128*128 bf16
    int* cnt_in    = (int*)(WF1 + 128 * 128);            // NA
    int* row_start = cnt_in + NA;                        // NA
    int* bsum      = row_start + NA;                     // 256
    int* boff      = bsum + 256;                         // 256
    unsigned* partial_out = (unsigned*)(boff + 256);     // CH*NP
    unsigned* partial_in  = partial_out + (size_t)CH * NP; // CH*NP
    unsigned short* csr = (unsigned short*)(partial_in + (size_t)CH * NP); // E u16

    // ---- atomic-free CSR build + norms + W fragment packs ----
    k_hist<<<2 * CH, 256, 0, stream>>>(src, dst, partial_out, partial_in, E, NP, Ec);
    k_merge<<<(NP + 255) / 256, 256, 0, stream>>>(partial_out, partial_in, cnt_in,
                                                  norm_out, norm_in, N, NP);
    k_scan_local<<<NB, 256, 0, stream>>>(cnt_in, row_start, bsum, N);
    k_scan_bsum_prep<<<1 + 128, 256, 0, stream>>>(bsum, boff, NB, W0, W1, WF0, WF1);
    k_add_off<<<NB, 256, 0, stream>>>(row_start, boff, g, N);
    int XB = (N * 32 + 255) / 256;
    k_fill_bx<<<CH + XB, 256, 0, stream>>>(src, dst, row_start, partial_in, csr,
                                           nid, z, emb, zt, norm_out, xA, N, E, NP, Ec);

    int gg_blocks = (N + 63) / 64;
    int gp_blocks = (N + 15) / 16;

    // layer 0: xA -> xB (fused gather+GEMM)
    k_gather_gemm<<<gg_blocks, 256, 0, stream>>>(xA, norm_in, csr, row_start, cnt_in,
                                                 WF0, b0, norm_out, xB, N);
    // layer 1: xB -> xA
    k_gather_gemm<<<gg_blocks, 256, 0, stream>>>(xB, norm_in, csr, row_start, cnt_in,
                                                 WF1, b1, norm_out, xA, N);
    // layer 2: gather fused with SumPool (GEMM commuted past pool via linearity)
    k_gather_pool<<<gp_blocks, 256, 0, stream>>>(xA, norm_in, csr, row_start, cnt_in,
                                                 gid, g, N);

    // tiny per-graph MLP head
    k_head<<<NG, 256, 0, stream>>>(g, gid, W2, b2, l1W, l1b, l2W, l2b, out, N);
}

// Round 3
// 277.850 us; speedup vs baseline: 1.1975x; 1.1975x over previous
//
#include <hip/hip_runtime.h>
#include <hip/hip_bf16.h>

// SEAL GCN: 3x GraphConv(norm=both) -> SumPool(graph_id sorted) -> MLP(128->128 relu ->200)
// N=50000, E=800000, feat=128, 512 graphs.
// R13: revert R12's regressions (CH back to 128, gather back to 8-deep ILP — compiler
//      capped VGPR=72 so 16-deep serialized), restructure fused gather+GEMM to 16
//      nodes/block (3125 blocks like R0's fast gather; 16-row MFMA tail, all waves
//      share A-frags, 2 column-tiles/wave). Pool keeps segmented non-atomic reduction.

#define FEAT 128
#define NG 512
#define CH 128       // edge chunks for hist/fill
#define NPMAX 12544  // max node-quads (N<=50176); 50KB static LDS
#define LDW 136      // LDS row stride in ushorts (bf16): 2-way-free banks for b128

typedef __attribute__((ext_vector_type(8))) short bf16x8;
typedef __attribute__((ext_vector_type(4))) float f32x4;

__device__ __forceinline__ float bf2f(unsigned short u) {
    union { unsigned int i; float f; } v; v.i = ((unsigned int)u) << 16; return v.f;
}
__device__ __forceinline__ unsigned short f2bf(float f) {
    unsigned int u = __float_as_uint(f);
    return (unsigned short)((u + 0x7FFFu + ((u >> 16) & 1u)) >> 16);  // RNE
}
__device__ __forceinline__ float lo16(unsigned u) { return __uint_as_float(u << 16); }
__device__ __forceinline__ float hi16(unsigned u) { return __uint_as_float(u & 0xFFFF0000u); }

// ---------------- chunked full-range histogram, packed u8, zero global atomics ----------------
__global__ __launch_bounds__(256) void k_hist(
        const int* __restrict__ src, const int* __restrict__ dst,
        unsigned* __restrict__ partial_out, unsigned* __restrict__ partial_in,
        int E, int NP, int Ec) {
    __shared__ unsigned h[NPMAX];
    int tid = threadIdx.x;
    int b = blockIdx.x;
    int c = b & (CH - 1);
    const int* __restrict__ arr = (b < CH) ? src : dst;
    unsigned* __restrict__ outp = ((b < CH) ? partial_out : partial_in) + (size_t)c * NP;
    for (int i = tid; i < NP; i += 256) h[i] = 0;
    __syncthreads();
    int e0 = c * Ec, e1 = min(E, e0 + Ec);
    for (int e = e0 + tid; e < e1; e += 256) {
        int v = arr[e];
        atomicAdd(&h[v >> 2], 1u << ((v & 3) * 8));
    }
    __syncthreads();
    for (int i = tid; i < NP; i += 256) outp[i] = h[i];
}

// ---------------- merge partials: totals + in-place exclusive chunk-prefix ----------------
__global__ void k_merge(unsigned* __restrict__ partial_out, unsigned* __restrict__ partial_in,
                        int* __restrict__ cnt_in, float* __restrict__ norm_out,
                        float* __restrict__ norm_in, int N, int NP) {
    int w = blockIdx.x * blockDim.x + threadIdx.x;
    if (w >= NP) return;
    unsigned run_in = 0, run_out = 0;
    for (int c = 0; c < CH; c++) {
        size_t idx = (size_t)c * NP + w;
        unsigned v = partial_in[idx];
        partial_in[idx] = run_in;
        run_in += v;
        run_out += partial_out[idx];
    }
    #pragma unroll
    for (int j = 0; j < 4; j++) {
        int node = w * 4 + j;
        if (node < N) {
            unsigned di = (run_in  >> (j * 8)) & 255u;
            unsigned dd = (run_out >> (j * 8)) & 255u;
            cnt_in[node]   = (int)di;
            norm_in[node]  = rsqrtf(fmaxf((float)di, 1.0f));
            norm_out[node] = rsqrtf(fmaxf((float)dd, 1.0f));
        }
    }
}

// ---------------- 2-level exclusive scan of cnt_in -> row_start ----------------
__global__ void k_scan_local(const int* __restrict__ cnt, int* __restrict__ excl,
                             int* __restrict__ bsum, int N) {
    __shared__ int s[256];
    int x = threadIdx.x;
    int i = blockIdx.x * 256 + x;
    int v = (i < N) ? cnt[i] : 0;
    s[x] = v;
    __syncthreads();
    for (int off = 1; off < 256; off <<= 1) {
        int t = (x >= off) ? s[x - off] : 0;
        __syncthreads();
        s[x] += t;
        __syncthreads();
    }
    if (i < N) excl[i] = s[x] - v;
    if (x == 255) bsum[blockIdx.x] = s[255];
}

// block 0: scan of block sums; blocks 1..128: pack W0,W1 -> bf16 MFMA B-fragment order
// WF[f][lane][e] with f=nt*4+fi, lane=q*16+c: value = W[k*128+n], n=nt*16+c, k=fi*32+q*8+e
__global__ void k_scan_bsum_prep(int* __restrict__ bsum, int* __restrict__ boff, int nb,
                                 const float* __restrict__ W0, const float* __restrict__ W1,
                                 unsigned short* __restrict__ WF0, unsigned short* __restrict__ WF1) {
    if (blockIdx.x == 0) {
        __shared__ int s[256];
        int x = threadIdx.x;
        int v = (x < nb) ? bsum[x] : 0;
        s[x] = v;
        __syncthreads();
        for (int off = 1; off < 256; off <<= 1) {
            int t = (x >= off) ? s[x - off] : 0;
            __syncthreads();
            s[x] += t;
            __syncthreads();
        }
        if (x < nb) boff[x] = s[x] - v;
    } else {
        int t = ((int)blockIdx.x - 1) * 256 + threadIdx.x;  // 0..32767
        const float* __restrict__ W = (t < 16384) ? W0 : W1;
        unsigned short* __restrict__ WF = (t < 16384) ? WF0 : WF1;
        int tt = t & 16383;
        int f = tt >> 9, l = (tt >> 3) & 63, e = tt & 7;
        int n = (f >> 2) * 16 + (l & 15);
        int k = (f & 3) * 32 + (l >> 4) * 8 + e;
        WF[tt] = f2bf(W[k * 128 + n]);
    }
}

__global__ void k_add_off(int* __restrict__ row_start, const int* __restrict__ boff,
                          float* __restrict__ g, int N) {
    int i = blockIdx.x * blockDim.x + threadIdx.x;
    int stride = gridDim.x * blockDim.x;
    if (i < N) row_start[i] += boff[i >> 8];
    for (int j = i; j < NG * FEAT; j += stride) g[j] = 0.f;  // zero pooled accum
}

// ---------------- chunked CSR fill (LDS cursors, packed u8, u16 csr) + build x0 ----------------
__global__ __launch_bounds__(256) void k_fill_bx(
        const int* __restrict__ src, const int* __restrict__ dst,
        const int* __restrict__ row_start, const unsigned* __restrict__ partial_in,
        unsigned short* __restrict__ csr,
        const int* __restrict__ nid, const int* __restrict__ z,
        const float* __restrict__ emb, const float* __restrict__ zt,
        const float* __restrict__ nout, unsigned short* __restrict__ x,
        int N, int E, int NP, int Ec) {
    if ((int)blockIdx.x < CH) {
        __shared__ unsigned cur[NPMAX];
        int tid = threadIdx.x;
        int c = blockIdx.x;
        const unsigned* __restrict__ pre = partial_in + (size_t)c * NP;
        for (int i = tid; i < NP; i += 256) cur[i] = pre[i];
        __syncthreads();
        int e0 = c * Ec, e1 = min(E, e0 + Ec);
        for (int e = e0 + tid; e < e1; e += 256) {
            int d = dst[e], s = src[e];
            int sh = (d & 3) * 8;
            unsigned t = atomicAdd(&cur[d >> 2], 1u << sh);
            int off = (int)((t >> sh) & 255u);
            csr[row_start[d] + off] = (unsigned short)s;
        }
    } else {
        int tid = ((int)blockIdx.x - CH) * 256 + threadIdx.x;
        int i = tid >> 5, q = tid & 31;
        if (i < N) {
            float4 v;
            if (q < 16) v = ((const float4*)emb)[(size_t)nid[i] * 16 + q];
            else        v = ((const float4*)zt)[(size_t)z[i] * 16 + (q - 16)];
            float w = nout[i];
            ushort4 u;
            u.x = f2bf(v.x * w); u.y = f2bf(v.y * w);
            u.z = f2bf(v.z * w); u.w = f2bf(v.w * w);
            ((ushort4*)x)[(size_t)i * 32 + q] = u;
        }
    }
}

// ---------------- gather core: b128 loads, 16 lanes/node, 8-deep ILP ----------------
#define ACC8(u)                                                                  \
    a0 += lo16(u.x); a1 += hi16(u.x); a2 += lo16(u.y); a3 += hi16(u.y);          \
    a4 += lo16(u.z); a5 += hi16(u.z); a6 += lo16(u.w); a7 += hi16(u.w);

#define GATHER_LOOP                                                              \
    {                                                                            \
        int base = row_start[node];                                              \
        int n = cnt_in[node];                                                    \
        const uint4* xp = (const uint4*)x;  /* row = 16 uint4 */                 \
        for (int j0 = 0; j0 < n; j0 += 16) {                                     \
            int rem = n - j0;                                                    \
            int m = rem < 16 ? rem : 16;                                         \
            int e = (int)csr[base + j0 + (ql < m ? ql : 0)];                     \
            int j = 0;                                                           \
            for (; j + 8 <= m; j += 8) {                                         \
                int s0 = __shfl(e, j + 0, 16), s1 = __shfl(e, j + 1, 16);        \
                int s2 = __shfl(e, j + 2, 16), s3 = __shfl(e, j + 3, 16);        \
                int s4 = __shfl(e, j + 4, 16), s5 = __shfl(e, j + 5, 16);        \
                int s6 = __shfl(e, j + 6, 16), s7 = __shfl(e, j + 7, 16);        \
                uint4 u0 = xp[(size_t)s0 * 16 + ql];                             \
                uint4 u1 = xp[(size_t)s1 * 16 + ql];                             \
                uint4 u2 = xp[(size_t)s2 * 16 + ql];                             \
                uint4 u3 = xp[(size_t)s3 * 16 + ql];                             \
                uint4 u4 = xp[(size_t)s4 * 16 + ql];                             \
                uint4 u5 = xp[(size_t)s5 * 16 + ql];                             \
                uint4 u6 = xp[(size_t)s6 * 16 + ql];                             \
                uint4 u7 = xp[(size_t)s7 * 16 + ql];                             \
                ACC8(u0) ACC8(u1) ACC8(u2) ACC8(u3)                              \
                ACC8(u4) ACC8(u5) ACC8(u6) ACC8(u7)                              \
            }                                                                    \
            for (; j + 4 <= m; j += 4) {                                         \
                int s0 = __shfl(e, j + 0, 16), s1 = __shfl(e, j + 1, 16);        \
                int s2 = __shfl(e, j + 2, 16), s3 = __shfl(e, j + 3, 16);        \
                uint4 u0 = xp[(size_t)s0 * 16 + ql];                             \
                uint4 u1 = xp[(size_t)s1 * 16 + ql];                             \
                uint4 u2 = xp[(size_t)s2 * 16 + ql];                             \
                uint4 u3 = xp[(size_t)s3 * 16 + ql];                             \
                ACC8(u0) ACC8(u1) ACC8(u2) ACC8(u3)                              \
            }                                                                    \
            for (; j < m; j++) {                                                 \
                int s = __shfl(e, j, 16);                                        \
                uint4 u = xp[(size_t)s * 16 + ql];                               \
                ACC8(u)                                                          \
            }                                                                    \
        }                                                                        \
    }

// ---------------- fused gather + MFMA GEMM, 16 nodes/block ----------------
// Gather: all 256 threads = 16 nodes x 16 lanes, single round (R0 granularity, 3125
// blocks -> good balance). GEMM: 16-row tile; all 4 waves share the same A-frags from
// LDS; wave w computes column-tiles {2w, 2w+1} (8 MFMAs/wave); W frags from L2 WF.
__global__ __launch_bounds__(256) void k_gather_gemm(
        const unsigned short* __restrict__ x, const float* __restrict__ nin,
        const unsigned short* __restrict__ csr, const int* __restrict__ row_start,
        const int* __restrict__ cnt_in, const unsigned short* __restrict__ WF,
        const float* __restrict__ bias, const float* __restrict__ nout,
        unsigned short* __restrict__ y, int N) {
    __shared__ unsigned short As[16 * LDW];  // 4.3KB
    int tid = threadIdx.x;
    int nb = blockIdx.x * 16;
    int ql = tid & 15;
    int nl = tid >> 4;
    int node = nb + nl;

    float a0 = 0.f, a1 = 0.f, a2 = 0.f, a3 = 0.f;
    float a4 = 0.f, a5 = 0.f, a6 = 0.f, a7 = 0.f;
    if (node < N) {
        GATHER_LOOP
        float ni = nin[node];
        a0 *= ni; a1 *= ni; a2 *= ni; a3 *= ni;
        a4 *= ni; a5 *= ni; a6 *= ni; a7 *= ni;
    }
    uint4 o;
    o.x = (unsigned)f2bf(a0) | ((unsigned)f2bf(a1) << 16);
    o.y = (unsigned)f2bf(a2) | ((unsigned)f2bf(a3) << 16);
    o.z = (unsigned)f2bf(a4) | ((unsigned)f2bf(a5) << 16);
    o.w = (unsigned)f2bf(a6) | ((unsigned)f2bf(a7) << 16);
    *(uint4*)(As + nl * LDW + ql * 8) = o;
    __syncthreads();

    int lane = tid & 63;
    int wv = tid >> 6;
    int c = lane & 15, q = lane >> 4;

    // shared 16-row A-fragments (identical across waves: LDS broadcast)
    const unsigned short* ap = As + c * LDW + q * 8;
    bf16x8 fa0 = *(const bf16x8*)(ap);
    bf16x8 fa1 = *(const bf16x8*)(ap + 32);
    bf16x8 fa2 = *(const bf16x8*)(ap + 64);
    bf16x8 fa3 = *(const bf16x8*)(ap + 96);
    const bf16x8* __restrict__ wf = (const bf16x8*)WF;
    __syncthreads();  // A-frags in regs; safe to overwrite As with outputs

    #pragma unroll
    for (int t = 0; t < 2; t++) {
        int nt = wv * 2 + t;
        bf16x8 fb0 = wf[(nt * 4 + 0) * 64 + lane];
        bf16x8 fb1 = wf[(nt * 4 + 1) * 64 + lane];
        bf16x8 fb2 = wf[(nt * 4 + 2) * 64 + lane];
        bf16x8 fb3 = wf[(nt * 4 + 3) * 64 + lane];
        float bb = bias[nt * 16 + c];
        f32x4 acc = {bb, bb, bb, bb};
        acc = __builtin_amdgcn_mfma_f32_16x16x32_bf16(fa0, fb0, acc, 0, 0, 0);
        acc = __builtin_amdgcn_mfma_f32_16x16x32_bf16(fa1, fb1, acc, 0, 0, 0);
        acc = __builtin_amdgcn_mfma_f32_16x16x32_bf16(fa2, fb2, acc, 0, 0, 0);
        acc = __builtin_amdgcn_mfma_f32_16x16x32_bf16(fa3, fb3, acc, 0, 0, 0);
        #pragma unroll
        for (int rr = 0; rr < 4; rr++) {
            int row = q * 4 + rr;
            float s = nout[min(nb + row, N - 1)];
            As[row * LDW + nt * 16 + c] = f2bf(fmaxf(acc[rr], 0.f) * s);
        }
    }
    __syncthreads();

    // coalesced store: 16 rows x 128 u16 = 256 x ushort4x2
    {
        int row = tid >> 4, seg = tid & 15;
        int nd = nb + row;
        if (nd < N) {
            const ushort4* p = (const ushort4*)(As + row * LDW + seg * 8);
            ushort4* d = (ushort4*)(y + (size_t)nd * 128 + seg * 8);
            d[0] = p[0]; d[1] = p[1];
        }
    }
}

// ---------------- fused layer-2 gather + SumPool: g[gid] += (A_hat x)[node] ----------------
// graph_id sorted -> per-node LDS rows, then non-atomic segmented reduction over the
// sorted gid runs (<=16 per block); one coalesced global-atomic set per run-half.
__global__ __launch_bounds__(256) void k_gather_pool(
        const unsigned short* __restrict__ x, const float* __restrict__ nin,
        const unsigned short* __restrict__ csr, const int* __restrict__ row_start,
        const int* __restrict__ cnt_in, const int* __restrict__ gid,
        float* __restrict__ g, int N) {
    __shared__ __align__(16) float gl[16][132];  // per-node partials, +4 pad
    __shared__ int slots[16];
    int tid = threadIdx.x;
    int nb = blockIdx.x * 16;
    int ql = tid & 15;
    int nl = tid >> 4;
    int node = nb + nl;

    float a0 = 0.f, a1 = 0.f, a2 = 0.f, a3 = 0.f;
    float a4 = 0.f, a5 = 0.f, a6 = 0.f, a7 = 0.f;
    int slot = -1;
    if (node < N) {
        GATHER_LOOP
        float ni = nin[node];
        a0 *= ni; a1 *= ni; a2 *= ni; a3 *= ni;
        a4 *= ni; a5 *= ni; a6 *= ni; a7 *= ni;
        slot = gid[node];
    }
    float4* row = (float4*)&gl[nl][ql * 8];
    row[0] = make_float4(a0, a1, a2, a3);
    row[1] = make_float4(a4, a5, a6, a7);
    if (ql == 0) slots[nl] = slot;
    __syncthreads();

    int h = tid >> 7;       // 0/1: nodes 0-7 / 8-15
    int j = tid & 127;
    int prev = -1;
    float acc = 0.f;
    #pragma unroll
    for (int i = h * 8; i < h * 8 + 8; i++) {
        int s = slots[i];
        if (s != prev) {
            if (prev >= 0) atomicAdd(&g[(size_t)prev * FEAT + j], acc);
            acc = 0.f;
            prev = s;
        }
        acc += gl[i][j];
    }
    if (prev >= 0) atomicAdd(&g[(size_t)prev * FEAT + j], acc);
}

// ---------------- head: ys = g@W2 + cnt*b2 ; out = relu(ys@l1W+l1b)@l2W+l2b ----------------
__global__ __launch_bounds__(256) void k_head(
        const float* __restrict__ g, const int* __restrict__ gid,
        const float* __restrict__ W2, const float* __restrict__ b2,
        const float* __restrict__ l1W, const float* __restrict__ l1b,
        const float* __restrict__ l2W, const float* __restrict__ l2b,
        float* __restrict__ out, int N) {
    __shared__ float gs[128];
    __shared__ float ys[128];
    __shared__ float hs[128];
    int gi = blockIdx.x, tid = threadIdx.x;

    int lo = 0, hi = N;
    while (lo < hi) { int m = (lo + hi) >> 1; if (gid[m] < gi) lo = m + 1; else hi = m; }
    int s0 = lo;
    lo = 0; hi = N;
    while (lo < hi) { int m = (lo + hi) >> 1; if (gid[m] < gi + 1) lo = m + 1; else hi = m; }
    float cnt = (float)(lo - s0);

    if (tid < 128) gs[tid] = g[(size_t)gi * FEAT + tid];
    __syncthreads();
    if (tid < 128) {
        float a = cnt * b2[tid];
        for (int k = 0; k < 128; k++) a += gs[k] * W2[(size_t)k * 128 + tid];
        ys[tid] = a;
    }
    __syncthreads();
    if (tid < 128) {
        float a = l1b[tid];
        for (int k = 0; k < 128; k++) a += ys[k] * l1W[(size_t)k * 128 + tid];
        hs[tid] = fmaxf(a, 0.f);
    }
    __syncthreads();
    if (tid < 200) {
        float a = l2b[tid];
        for (int k = 0; k < 128; k++) a += hs[k] * l2W[(size_t)k * 200 + tid];
        out[(size_t)gi * 200 + tid] = a;
    }
}

extern "C" void kernel_launch(void* const* d_in, const int* in_sizes, int n_in,
                              void* d_out, int out_size, void* d_ws, size_t ws_size,
                              hipStream_t stream) {
    const int*   nid = (const int*)d_in[0];
    const int*   z   = (const int*)d_in[1];
    const int*   src = (const int*)d_in[2];
    const int*   dst = (const int*)d_in[3];
    const int*   gid = (const int*)d_in[4];
    const float* emb = (const float*)d_in[5];
    const float* zt  = (const float*)d_in[6];
    const float* W0  = (const float*)d_in[7];
    const float* b0  = (const float*)d_in[8];
    const float* W1  = (const float*)d_in[9];
    const float* b1  = (const float*)d_in[10];
    const float* W2  = (const float*)d_in[11];
    const float* b2  = (const float*)d_in[12];
    const float* l1W = (const float*)d_in[13];
    const float* l1b = (const float*)d_in[14];
    const float* l2W = (const float*)d_in[15];
    const float* l2b = (const float*)d_in[16];
    float* out = (float*)d_out;

    const int N = in_sizes[0];
    const int E = in_sizes[2];
    const int NB = (N + 255) / 256;     // scan blocks (<=256 required)
    const int NP = (N + 3) / 4;         // node-quads (<= NPMAX)
    const int Ec = (E + CH - 1) / CH;   // edges per chunk

    // ---- workspace ----
    size_t NA = (size_t)((N + 63) & ~63);
    float* norm_out = (float*)d_ws;                      // NA
    float* norm_in  = norm_out + NA;                     // NA
    float* g        = norm_in + NA;                      // NG*FEAT fp32 pooled accum
    unsigned short* xA  = (unsigned short*)(g + (size_t)NG * FEAT);  // N*128 bf16
    unsigned short* xB  = xA + (size_t)N * FEAT;         // N*128 bf16
    unsigned short* WF0 = xB + (size_t)N * FEAT;         // 128*128 bf16 (fragment order)
    unsigned short* WF1 = WF0 + 128 * 128;               // 128*128 bf16
    int* cnt_in    = (int*)(WF1 + 128 * 128);            // NA
    int* row_start = cnt_in + NA;                        // NA
    int* bsum      = row_start + NA;                     // 256
    int* boff      = bsum + 256;                         // 256
    unsigned* partial_out = (unsigned*)(boff + 256);     // CH*NP
    unsigned* partial_in  = partial_out + (size_t)CH * NP; // CH*NP
    unsigned short* csr = (unsigned short*)(partial_in + (size_t)CH * NP); // E u16

    // ---- atomic-free CSR build + norms + W fragment packs ----
    k_hist<<<2 * CH, 256, 0, stream>>>(src, dst, partial_out, partial_in, E, NP, Ec);
    k_merge<<<(NP + 255) / 256, 256, 0, stream>>>(partial_out, partial_in, cnt_in,
                                                  norm_out, norm_in, N, NP);
    k_scan_local<<<NB, 256, 0, stream>>>(cnt_in, row_start, bsum, N);
    k_scan_bsum_prep<<<1 + 128, 256, 0, stream>>>(bsum, boff, NB, W0, W1, WF0, WF1);
    k_add_off<<<NB, 256, 0, stream>>>(row_start, boff, g, N);
    int XB = (N * 32 + 255) / 256;
    k_fill_bx<<<CH + XB, 256, 0, stream>>>(src, dst, row_start, partial_in, csr,
                                           nid, z, emb, zt, norm_out, xA, N, E, NP, Ec);

    int gg_blocks = (N + 15) / 16;

    // layer 0: xA -> xB (fused gather+GEMM, 16 nodes/block)
    k_gather_gemm<<<gg_blocks, 256, 0, stream>>>(xA, norm_in, csr, row_start, cnt_in,
                                                 WF0, b0, norm_out, xB, N);
    // layer 1: xB -> xA
    k_gather_gemm<<<gg_blocks, 256, 0, stream>>>(xB, norm_in, csr, row_start, cnt_in,
                                                 WF1, b1, norm_out, xA, N);
    // layer 2: gather fused with SumPool (GEMM commuted past pool via linearity)
    k_gather_pool<<<gg_blocks, 256, 0, stream>>>(xA, norm_in, csr, row_start, cnt_in,
                                                 gid, g, N);

    // tiny per-graph MLP head
    k_head<<<NG, 256, 0, stream>>>(g, gid, W2, b2, l1W, l1b, l2W, l2b, out, N);
}

// Round 4
// 276.274 us; speedup vs baseline: 1.2043x; 1.0057x over previous
//
#include <hip/hip_runtime.h>
#include <hip/hip_bf16.h>

// SEAL GCN: 3x GraphConv(norm=both) -> SumPool(graph_id sorted) -> MLP(128->128 relu ->200)
// N=50000, E=800000, feat=128, 512 graphs.
// R14: R13 + (a) __launch_bounds__(256,8) on gather kernels: cap VGPR<=64 so 8 waves/SIMD
//      resident (VGPR=72 was halving occupancy -> latency-bound gathers starved of TLP);
//      (b) k_merge rebuilt as tiled parallel scan (392 blocks, 32 quads x 128 chunks LDS
//      tile) replacing the 49-block serial-128 chunk walk.

#define FEAT 128
#define NG 512
#define CH 128       // edge chunks for hist/fill
#define NPMAX 12544  // max node-quads (N<=50176); 50KB static LDS
#define LDW 136      // LDS row stride in ushorts (bf16): 2-way-free banks for b128

typedef __attribute__((ext_vector_type(8))) short bf16x8;
typedef __attribute__((ext_vector_type(4))) float f32x4;

__device__ __forceinline__ float bf2f(unsigned short u) {
    union { unsigned int i; float f; } v; v.i = ((unsigned int)u) << 16; return v.f;
}
__device__ __forceinline__ unsigned short f2bf(float f) {
    unsigned int u = __float_as_uint(f);
    return (unsigned short)((u + 0x7FFFu + ((u >> 16) & 1u)) >> 16);  // RNE
}
__device__ __forceinline__ float lo16(unsigned u) { return __uint_as_float(u << 16); }
__device__ __forceinline__ float hi16(unsigned u) { return __uint_as_float(u & 0xFFFF0000u); }

// ---------------- chunked full-range histogram, packed u8, zero global atomics ----------------
__global__ __launch_bounds__(256) void k_hist(
        const int* __restrict__ src, const int* __restrict__ dst,
        unsigned* __restrict__ partial_out, unsigned* __restrict__ partial_in,
        int E, int NP, int Ec) {
    __shared__ unsigned h[NPMAX];
    int tid = threadIdx.x;
    int b = blockIdx.x;
    int c = b & (CH - 1);
    const int* __restrict__ arr = (b < CH) ? src : dst;
    unsigned* __restrict__ outp = ((b < CH) ? partial_out : partial_in) + (size_t)c * NP;
    for (int i = tid; i < NP; i += 256) h[i] = 0;
    __syncthreads();
    int e0 = c * Ec, e1 = min(E, e0 + Ec);
    for (int e = e0 + tid; e < e1; e += 256) {
        int v = arr[e];
        atomicAdd(&h[v >> 2], 1u << ((v & 3) * 8));
    }
    __syncthreads();
    for (int i = tid; i < NP; i += 256) outp[i] = h[i];
}

// ---------------- merge partials: tiled parallel scan (32 quads x 128 chunks / block) ----------
// Replaces serial-128 chunk walk: per-block LDS tile, 8 threads/quad segmented scan.
// partial_in[c][w] <- exclusive prefix over chunks; totals -> cnt_in/norm_in/norm_out.
__global__ __launch_bounds__(256) void k_merge(
        unsigned* __restrict__ partial_out, unsigned* __restrict__ partial_in,
        int* __restrict__ cnt_in, float* __restrict__ norm_out,
        float* __restrict__ norm_in, int N, int NP) {
    __shared__ unsigned tile[CH][33];   // 128 x 33 u32 = 16.9KB (pad -> 2-way max)
    __shared__ unsigned sums[32][9];    // [quad][seg 0..7, total_in at 8]
    int q0 = blockIdx.x * 32;
    int tid = threadIdx.x;
    int qd = tid & 31, k = tid >> 5;    // 8 segs x 16 chunks per quad

    // ---- pass 1: partial_in -> exclusive prefix + totals ----
    for (int idx = tid; idx < 32 * CH; idx += 256) {
        int c = idx >> 5, q = idx & 31;
        unsigned v = 0;
        if (q0 + q < NP) v = partial_in[(size_t)c * NP + q0 + q];
        tile[c][q] = v;
    }
    __syncthreads();
    unsigned loc = 0;
    #pragma unroll
    for (int i = 0; i < 16; i++) loc += tile[k * 16 + i][qd];
    sums[qd][k] = loc;
    __syncthreads();
    if (k == 0) {
        unsigned r = 0;
        #pragma unroll
        for (int j = 0; j < 8; j++) { unsigned v = sums[qd][j]; sums[qd][j] = r; r += v; }
        sums[qd][8] = r;   // total in-degree (packed u8 x4)
    }
    __syncthreads();
    unsigned run = sums[qd][k];
    #pragma unroll
    for (int i = 0; i < 16; i++) {
        unsigned v = tile[k * 16 + i][qd];
        tile[k * 16 + i][qd] = run;
        run += v;
    }
    __syncthreads();
    for (int idx = tid; idx < 32 * CH; idx += 256) {
        int c = idx >> 5, q = idx & 31;
        if (q0 + q < NP) partial_in[(size_t)c * NP + q0 + q] = tile[c][q];
    }
    __syncthreads();

    // ---- pass 2: partial_out totals only ----
    for (int idx = tid; idx < 32 * CH; idx += 256) {
        int c = idx >> 5, q = idx & 31;
        unsigned v = 0;
        if (q0 + q < NP) v = partial_out[(size_t)c * NP + q0 + q];
        tile[c][q] = v;
    }
    __syncthreads();
    unsigned loco = 0;
    #pragma unroll
    for (int i = 0; i < 16; i++) loco += tile[k * 16 + i][qd];
    sums[qd][k] = loco;   // safe: prefix values already consumed; [8] untouched
    __syncthreads();
    if (k == 0) {
        unsigned tot = 0;
        #pragma unroll
        for (int j = 0; j < 8; j++) tot += sums[qd][j];
        unsigned rin = sums[qd][8];
        int w = q0 + qd;
        if (w < NP) {
            #pragma unroll
            for (int j = 0; j < 4; j++) {
                int node = w * 4 + j;
                if (node < N) {
                    unsigned di = (rin >> (j * 8)) & 255u;
                    unsigned dd = (tot >> (j * 8)) & 255u;
                    cnt_in[node]   = (int)di;
                    norm_in[node]  = rsqrtf(fmaxf((float)di, 1.0f));
                    norm_out[node] = rsqrtf(fmaxf((float)dd, 1.0f));
                }
            }
        }
    }
}

// ---------------- 2-level exclusive scan of cnt_in -> row_start ----------------
__global__ void k_scan_local(const int* __restrict__ cnt, int* __restrict__ excl,
                             int* __restrict__ bsum, int N) {
    __shared__ int s[256];
    int x = threadIdx.x;
    int i = blockIdx.x * 256 + x;
    int v = (i < N) ? cnt[i] : 0;
    s[x] = v;
    __syncthreads();
    for (int off = 1; off < 256; off <<= 1) {
        int t = (x >= off) ? s[x - off] : 0;
        __syncthreads();
        s[x] += t;
        __syncthreads();
    }
    if (i < N) excl[i] = s[x] - v;
    if (x == 255) bsum[blockIdx.x] = s[255];
}

// block 0: scan of block sums; blocks 1..128: pack W0,W1 -> bf16 MFMA B-fragment order
// WF[f][lane][e] with f=nt*4+fi, lane=q*16+c: value = W[k*128+n], n=nt*16+c, k=fi*32+q*8+e
__global__ void k_scan_bsum_prep(int* __restrict__ bsum, int* __restrict__ boff, int nb,
                                 const float* __restrict__ W0, const float* __restrict__ W1,
                                 unsigned short* __restrict__ WF0, unsigned short* __restrict__ WF1) {
    if (blockIdx.x == 0) {
        __shared__ int s[256];
        int x = threadIdx.x;
        int v = (x < nb) ? bsum[x] : 0;
        s[x] = v;
        __syncthreads();
        for (int off = 1; off < 256; off <<= 1) {
            int t = (x >= off) ? s[x - off] : 0;
            __syncthreads();
            s[x] += t;
            __syncthreads();
        }
        if (x < nb) boff[x] = s[x] - v;
    } else {
        int t = ((int)blockIdx.x - 1) * 256 + threadIdx.x;  // 0..32767
        const float* __restrict__ W = (t < 16384) ? W0 : W1;
        unsigned short* __restrict__ WF = (t < 16384) ? WF0 : WF1;
        int tt = t & 16383;
        int f = tt >> 9, l = (tt >> 3) & 63, e = tt & 7;
        int n = (f >> 2) * 16 + (l & 15);
        int k = (f & 3) * 32 + (l >> 4) * 8 + e;
        WF[tt] = f2bf(W[k * 128 + n]);
    }
}

__global__ void k_add_off(int* __restrict__ row_start, const int* __restrict__ boff,
                          float* __restrict__ g, int N) {
    int i = blockIdx.x * blockDim.x + threadIdx.x;
    int stride = gridDim.x * blockDim.x;
    if (i < N) row_start[i] += boff[i >> 8];
    for (int j = i; j < NG * FEAT; j += stride) g[j] = 0.f;  // zero pooled accum
}

// ---------------- chunked CSR fill (LDS cursors, packed u8, u16 csr) + build x0 ----------------
__global__ __launch_bounds__(256) void k_fill_bx(
        const int* __restrict__ src, const int* __restrict__ dst,
        const int* __restrict__ row_start, const unsigned* __restrict__ partial_in,
        unsigned short* __restrict__ csr,
        const int* __restrict__ nid, const int* __restrict__ z,
        const float* __restrict__ emb, const float* __restrict__ zt,
        const float* __restrict__ nout, unsigned short* __restrict__ x,
        int N, int E, int NP, int Ec) {
    if ((int)blockIdx.x < CH) {
        __shared__ unsigned cur[NPMAX];
        int tid = threadIdx.x;
        int c = blockIdx.x;
        const unsigned* __restrict__ pre = partial_in + (size_t)c * NP;
        for (int i = tid; i < NP; i += 256) cur[i] = pre[i];
        __syncthreads();
        int e0 = c * Ec, e1 = min(E, e0 + Ec);
        for (int e = e0 + tid; e < e1; e += 256) {
            int d = dst[e], s = src[e];
            int sh = (d & 3) * 8;
            unsigned t = atomicAdd(&cur[d >> 2], 1u << sh);
            int off = (int)((t >> sh) & 255u);
            csr[row_start[d] + off] = (unsigned short)s;
        }
    } else {
        int tid = ((int)blockIdx.x - CH) * 256 + threadIdx.x;
        int i = tid >> 5, q = tid & 31;
        if (i < N) {
            float4 v;
            if (q < 16) v = ((const float4*)emb)[(size_t)nid[i] * 16 + q];
            else        v = ((const float4*)zt)[(size_t)z[i] * 16 + (q - 16)];
            float w = nout[i];
            ushort4 u;
            u.x = f2bf(v.x * w); u.y = f2bf(v.y * w);
            u.z = f2bf(v.z * w); u.w = f2bf(v.w * w);
            ((ushort4*)x)[(size_t)i * 32 + q] = u;
        }
    }
}

// ---------------- gather core: b128 loads, 16 lanes/node, 8-deep ILP ----------------
#define ACC8(u)                                                                  \
    a0 += lo16(u.x); a1 += hi16(u.x); a2 += lo16(u.y); a3 += hi16(u.y);          \
    a4 += lo16(u.z); a5 += hi16(u.z); a6 += lo16(u.w); a7 += hi16(u.w);

#define GATHER_LOOP                                                              \
    {                                                                            \
        int base = row_start[node];                                              \
        int n = cnt_in[node];                                                    \
        const uint4* xp = (const uint4*)x;  /* row = 16 uint4 */                 \
        for (int j0 = 0; j0 < n; j0 += 16) {                                     \
            int rem = n - j0;                                                    \
            int m = rem < 16 ? rem : 16;                                         \
            int e = (int)csr[base + j0 + (ql < m ? ql : 0)];                     \
            int j = 0;                                                           \
            for (; j + 8 <= m; j += 8) {                                         \
                int s0 = __shfl(e, j + 0, 16), s1 = __shfl(e, j + 1, 16);        \
                int s2 = __shfl(e, j + 2, 16), s3 = __shfl(e, j + 3, 16);        \
                int s4 = __shfl(e, j + 4, 16), s5 = __shfl(e, j + 5, 16);        \
                int s6 = __shfl(e, j + 6, 16), s7 = __shfl(e, j + 7, 16);        \
                uint4 u0 = xp[(size_t)s0 * 16 + ql];                             \
                uint4 u1 = xp[(size_t)s1 * 16 + ql];                             \
                uint4 u2 = xp[(size_t)s2 * 16 + ql];                             \
                uint4 u3 = xp[(size_t)s3 * 16 + ql];                             \
                uint4 u4 = xp[(size_t)s4 * 16 + ql];                             \
                uint4 u5 = xp[(size_t)s5 * 16 + ql];                             \
                uint4 u6 = xp[(size_t)s6 * 16 + ql];                             \
                uint4 u7 = xp[(size_t)s7 * 16 + ql];                             \
                ACC8(u0) ACC8(u1) ACC8(u2) ACC8(u3)                              \
                ACC8(u4) ACC8(u5) ACC8(u6) ACC8(u7)                              \
            }                                                                    \
            for (; j + 4 <= m; j += 4) {                                         \
                int s0 = __shfl(e, j + 0, 16), s1 = __shfl(e, j + 1, 16);        \
                int s2 = __shfl(e, j + 2, 16), s3 = __shfl(e, j + 3, 16);        \
                uint4 u0 = xp[(size_t)s0 * 16 + ql];                             \
                uint4 u1 = xp[(size_t)s1 * 16 + ql];                             \
                uint4 u2 = xp[(size_t)s2 * 16 + ql];                             \
                uint4 u3 = xp[(size_t)s3 * 16 + ql];                             \
                ACC8(u0) ACC8(u1) ACC8(u2) ACC8(u3)                              \
            }                                                                    \
            for (; j < m; j++) {                                                 \
                int s = __shfl(e, j, 16);                                        \
                uint4 u = xp[(size_t)s * 16 + ql];                               \
                ACC8(u)                                                          \
            }                                                                    \
        }                                                                        \
    }

// ---------------- fused gather + MFMA GEMM, 16 nodes/block ----------------
// Gather: all 256 threads = 16 nodes x 16 lanes, single round. GEMM: 16-row tile; all 4
// waves share the same A-frags from LDS; wave w computes column-tiles {2w, 2w+1}.
// launch_bounds(256,8): cap VGPR<=64 -> 8 waves/SIMD resident (latency-bound gather).
__global__ __launch_bounds__(256, 8) void k_gather_gemm(
        const unsigned short* __restrict__ x, const float* __restrict__ nin,
        const unsigned short* __restrict__ csr, const int* __restrict__ row_start,
        const int* __restrict__ cnt_in, const unsigned short* __restrict__ WF,
        const float* __restrict__ bias, const float* __restrict__ nout,
        unsigned short* __restrict__ y, int N) {
    __shared__ unsigned short As[16 * LDW];  // 4.3KB
    int tid = threadIdx.x;
    int nb = blockIdx.x * 16;
    int ql = tid & 15;
    int nl = tid >> 4;
    int node = nb + nl;

    float a0 = 0.f, a1 = 0.f, a2 = 0.f, a3 = 0.f;
    float a4 = 0.f, a5 = 0.f, a6 = 0.f, a7 = 0.f;
    if (node < N) {
        GATHER_LOOP
        float ni = nin[node];
        a0 *= ni; a1 *= ni; a2 *= ni; a3 *= ni;
        a4 *= ni; a5 *= ni; a6 *= ni; a7 *= ni;
    }
    uint4 o;
    o.x = (unsigned)f2bf(a0) | ((unsigned)f2bf(a1) << 16);
    o.y = (unsigned)f2bf(a2) | ((unsigned)f2bf(a3) << 16);
    o.z = (unsigned)f2bf(a4) | ((unsigned)f2bf(a5) << 16);
    o.w = (unsigned)f2bf(a6) | ((unsigned)f2bf(a7) << 16);
    *(uint4*)(As + nl * LDW + ql * 8) = o;
    __syncthreads();

    int lane = tid & 63;
    int wv = tid >> 6;
    int c = lane & 15, q = lane >> 4;

    // shared 16-row A-fragments (identical across waves: LDS broadcast)
    const unsigned short* ap = As + c * LDW + q * 8;
    bf16x8 fa0 = *(const bf16x8*)(ap);
    bf16x8 fa1 = *(const bf16x8*)(ap + 32);
    bf16x8 fa2 = *(const bf16x8*)(ap + 64);
    bf16x8 fa3 = *(const bf16x8*)(ap + 96);
    const bf16x8* __restrict__ wf = (const bf16x8*)WF;
    __syncthreads();  // A-frags in regs; safe to overwrite As with outputs

    #pragma unroll
    for (int t = 0; t < 2; t++) {
        int nt = wv * 2 + t;
        bf16x8 fb0 = wf[(nt * 4 + 0) * 64 + lane];
        bf16x8 fb1 = wf[(nt * 4 + 1) * 64 + lane];
        bf16x8 fb2 = wf[(nt * 4 + 2) * 64 + lane];
        bf16x8 fb3 = wf[(nt * 4 + 3) * 64 + lane];
        float bb = bias[nt * 16 + c];
        f32x4 acc = {bb, bb, bb, bb};
        acc = __builtin_amdgcn_mfma_f32_16x16x32_bf16(fa0, fb0, acc, 0, 0, 0);
        acc = __builtin_amdgcn_mfma_f32_16x16x32_bf16(fa1, fb1, acc, 0, 0, 0);
        acc = __builtin_amdgcn_mfma_f32_16x16x32_bf16(fa2, fb2, acc, 0, 0, 0);
        acc = __builtin_amdgcn_mfma_f32_16x16x32_bf16(fa3, fb3, acc, 0, 0, 0);
        #pragma unroll
        for (int rr = 0; rr < 4; rr++) {
            int row = q * 4 + rr;
            float s = nout[min(nb + row, N - 1)];
            As[row * LDW + nt * 16 + c] = f2bf(fmaxf(acc[rr], 0.f) * s);
        }
    }
    __syncthreads();

    // coalesced store: 16 rows x 128 u16 = 256 x ushort4x2
    {
        int row = tid >> 4, seg = tid & 15;
        int nd = nb + row;
        if (nd < N) {
            const ushort4* p = (const ushort4*)(As + row * LDW + seg * 8);
            ushort4* d = (ushort4*)(y + (size_t)nd * 128 + seg * 8);
            d[0] = p[0]; d[1] = p[1];
        }
    }
}

// ---------------- fused layer-2 gather + SumPool: g[gid] += (A_hat x)[node] ----------------
// graph_id sorted -> per-node LDS rows, then non-atomic segmented reduction over the
// sorted gid runs (<=16 per block); one coalesced global-atomic set per run-half.
__global__ __launch_bounds__(256, 8) void k_gather_pool(
        const unsigned short* __restrict__ x, const float* __restrict__ nin,
        const unsigned short* __restrict__ csr, const int* __restrict__ row_start,
        const int* __restrict__ cnt_in, const int* __restrict__ gid,
        float* __restrict__ g, int N) {
    __shared__ __align__(16) float gl[16][132];  // per-node partials, +4 pad
    __shared__ int slots[16];
    int tid = threadIdx.x;
    int nb = blockIdx.x * 16;
    int ql = tid & 15;
    int nl = tid >> 4;
    int node = nb + nl;

    float a0 = 0.f, a1 = 0.f, a2 = 0.f, a3 = 0.f;
    float a4 = 0.f, a5 = 0.f, a6 = 0.f, a7 = 0.f;
    int slot = -1;
    if (node < N) {
        GATHER_LOOP
        float ni = nin[node];
        a0 *= ni; a1 *= ni; a2 *= ni; a3 *= ni;
        a4 *= ni; a5 *= ni; a6 *= ni; a7 *= ni;
        slot = gid[node];
    }
    float4* row = (float4*)&gl[nl][ql * 8];
    row[0] = make_float4(a0, a1, a2, a3);
    row[1] = make_float4(a4, a5, a6, a7);
    if (ql == 0) slots[nl] = slot;
    __syncthreads();

    int h = tid >> 7;       // 0/1: nodes 0-7 / 8-15
    int j = tid & 127;
    int prev = -1;
    float acc = 0.f;
    #pragma unroll
    for (int i = h * 8; i < h * 8 + 8; i++) {
        int s = slots[i];
        if (s != prev) {
            if (prev >= 0) atomicAdd(&g[(size_t)prev * FEAT + j], acc);
            acc = 0.f;
            prev = s;
        }
        acc += gl[i][j];
    }
    if (prev >= 0) atomicAdd(&g[(size_t)prev * FEAT + j], acc);
}

// ---------------- head: ys = g@W2 + cnt*b2 ; out = relu(ys@l1W+l1b)@l2W+l2b ----------------
__global__ __launch_bounds__(256) void k_head(
        const float* __restrict__ g, const int* __restrict__ gid,
        const float* __restrict__ W2, const float* __restrict__ b2,
        const float* __restrict__ l1W, const float* __restrict__ l1b,
        const float* __restrict__ l2W, const float* __restrict__ l2b,
        float* __restrict__ out, int N) {
    __shared__ float gs[128];
    __shared__ float ys[128];
    __shared__ float hs[128];
    int gi = blockIdx.x, tid = threadIdx.x;

    int lo = 0, hi = N;
    while (lo < hi) { int m = (lo + hi) >> 1; if (gid[m] < gi) lo = m + 1; else hi = m; }
    int s0 = lo;
    lo = 0; hi = N;
    while (lo < hi) { int m = (lo + hi) >> 1; if (gid[m] < gi + 1) lo = m + 1; else hi = m; }
    float cnt = (float)(lo - s0);

    if (tid < 128) gs[tid] = g[(size_t)gi * FEAT + tid];
    __syncthreads();
    if (tid < 128) {
        float a = cnt * b2[tid];
        for (int k = 0; k < 128; k++) a += gs[k] * W2[(size_t)k * 128 + tid];
        ys[tid] = a;
    }
    __syncthreads();
    if (tid < 128) {
        float a = l1b[tid];
        for (int k = 0; k < 128; k++) a += ys[k] * l1W[(size_t)k * 128 + tid];
        hs[tid] = fmaxf(a, 0.f);
    }
    __syncthreads();
    if (tid < 200) {
        float a = l2b[tid];
        for (int k = 0; k < 128; k++) a += hs[k] * l2W[(size_t)k * 200 + tid];
        out[(size_t)gi * 200 + tid] = a;
    }
}

extern "C" void kernel_launch(void* const* d_in, const int* in_sizes, int n_in,
                              void* d_out, int out_size, void* d_ws, size_t ws_size,
                              hipStream_t stream) {
    const int*   nid = (const int*)d_in[0];
    const int*   z   = (const int*)d_in[1];
    const int*   src = (const int*)d_in[2];
    const int*   dst = (const int*)d_in[3];
    const int*   gid = (const int*)d_in[4];
    const float* emb = (const float*)d_in[5];
    const float* zt  = (const float*)d_in[6];
    const float* W0  = (const float*)d_in[7];
    const float* b0  = (const float*)d_in[8];
    const float* W1  = (const float*)d_in[9];
    const float* b1  = (const float*)d_in[10];
    const float* W2  = (const float*)d_in[11];
    const float* b2  = (const float*)d_in[12];
    const float* l1W = (const float*)d_in[13];
    const float* l1b = (const float*)d_in[14];
    const float* l2W = (const float*)d_in[15];
    const float* l2b = (const float*)d_in[16];
    float* out = (float*)d_out;

    const int N = in_sizes[0];
    const int E = in_sizes[2];
    const int NB = (N + 255) / 256;     // scan blocks (<=256 required)
    const int NP = (N + 3) / 4;         // node-quads (<= NPMAX)
    const int Ec = (E + CH - 1) / CH;   // edges per chunk

    // ---- workspace ----
    size_t NA = (size_t)((N + 63) & ~63);
    float* norm_out = (float*)d_ws;                      // NA
    float* norm_in  = norm_out + NA;                     // NA
    float* g        = norm_in + NA;                      // NG*FEAT fp32 pooled accum
    unsigned short* xA  = (unsigned short*)(g + (size_t)NG * FEAT);  // N*128 bf16
    unsigned short* xB  = xA + (size_t)N * FEAT;         // N*128 bf16
    unsigned short* WF0 = xB + (size_t)N * FEAT;         // 128*128 bf16 (fragment order)
    unsigned short* WF1 = WF0 + 128 * 128;               // 128*128 bf16
    int* cnt_in    = (int*)(WF1 + 128 * 128);            // NA
    int* row_start = cnt_in + NA;                        // NA
    int* bsum      = row_start + NA;                     // 256
    int* boff      = bsum + 256;                         // 256
    unsigned* partial_out = (unsigned*)(boff + 256);     // CH*NP
    unsigned* partial_in  = partial_out + (size_t)CH * NP; // CH*NP
    unsigned short* csr = (unsigned short*)(partial_in + (size_t)CH * NP); // E u16

    // ---- atomic-free CSR build + norms + W fragment packs ----
    k_hist<<<2 * CH, 256, 0, stream>>>(src, dst, partial_out, partial_in, E, NP, Ec);
    k_merge<<<(NP + 31) / 32, 256, 0, stream>>>(partial_out, partial_in, cnt_in,
                                                norm_out, norm_in, N, NP);
    k_scan_local<<<NB, 256, 0, stream>>>(cnt_in, row_start, bsum, N);
    k_scan_bsum_prep<<<1 + 128, 256, 0, stream>>>(bsum, boff, NB, W0, W1, WF0, WF1);
    k_add_off<<<NB, 256, 0, stream>>>(row_start, boff, g, N);
    int XB = (N * 32 + 255) / 256;
    k_fill_bx<<<CH + XB, 256, 0, stream>>>(src, dst, row_start, partial_in, csr,
                                           nid, z, emb, zt, norm_out, xA, N, E, NP, Ec);

    int gg_blocks = (N + 15) / 16;

    // layer 0: xA -> xB (fused gather+GEMM, 16 nodes/block)
    k_gather_gemm<<<gg_blocks, 256, 0, stream>>>(xA, norm_in, csr, row_start, cnt_in,
                                                 WF0, b0, norm_out, xB, N);
    // layer 1: xB -> xA
    k_gather_gemm<<<gg_blocks, 256, 0, stream>>>(xB, norm_in, csr, row_start, cnt_in,
                                                 WF1, b1, norm_out, xA, N);
    // layer 2: gather fused with SumPool (GEMM commuted past pool via linearity)
    k_gather_pool<<<gg_blocks, 256, 0, stream>>>(xA, norm_in, csr, row_start, cnt_in,
                                                 gid, g, N);

    // tiny per-graph MLP head
    k_head<<<NG, 256, 0, stream>>>(g, gid, W2, b2, l1W, l1b, l2W, l2b, out, N);
}